// Round 17
// baseline (201.053 us; speedup 1.0000x reference)
//
#include <hip/hip_runtime.h>
#include <math.h>

#define BB 4
#define SS 2048
#define DD 1024
#define HHD 16      // heads
#define HD 64       // head dim
#define DH 512      // indexer hidden
#define KSEL 614    // top-k count
#define KPAD 640    // padded to multiple of 64
#define MTOT (BB*SS)
#define NCH (KPAD/64)
#define MKV (BB*KPAD)   // 2560 gathered K/V rows

typedef __attribute__((ext_vector_type(8))) short bf16x8;
typedef __attribute__((ext_vector_type(4))) float f32x4;

#define LDS_CAST(p) ((__attribute__((address_space(3))) void*)(p))
#define GLB_CAST(p) ((const __attribute__((address_space(1))) void*)(p))

// Q pre-scale: (1/8) * log2(e) so attention can use exp2 directly
#define QK_SCALE 0.18033688011112042f

// ---------------- fp32 -> bf16 helpers (RNE)
__device__ inline short bf16rne(float v)
{
    unsigned u = __builtin_bit_cast(unsigned, v);
    return (short)((u + 0x7FFFu + ((u >> 16) & 1u)) >> 16);
}

__device__ inline void split1(float v, short& h, short& l)
{
    unsigned u = __builtin_bit_cast(unsigned, v);
    unsigned hr = (u + 0x7FFFu + ((u >> 16) & 1u)) >> 16;
    h = (short)hr;
    float hf = __builtin_bit_cast(float, hr << 16);
    float res = v - hf;
    unsigned u2 = __builtin_bit_cast(unsigned, res);
    unsigned lr = (u2 + 0x7FFFu + ((u2 >> 16) & 1u)) >> 16;
    l = (short)lr;
}

__global__ __launch_bounds__(256)
void split_convert(const float* __restrict__ in, short* __restrict__ hi,
                   short* __restrict__ lo, int n4)
{
    const int i = blockIdx.x * 256 + threadIdx.x;
    if (i >= n4) return;
    float4 v = reinterpret_cast<const float4*>(in)[i];
    short4 h, l;
    split1(v.x, h.x, l.x);
    split1(v.y, h.y, l.y);
    split1(v.z, h.z, l.z);
    split1(v.w, h.w, l.w);
    reinterpret_cast<short4*>(hi)[i] = h;
    reinterpret_cast<short4*>(lo)[i] = l;
}

// fused weight splits: y=0 wq(hi), 1 wk(hi), 2 wv(hi), 3 wo(hi), 4 wi1(hi+lo), 5 bkv concat
__global__ __launch_bounds__(256)
void split_weights(const float* __restrict__ wq, const float* __restrict__ wk,
                   const float* __restrict__ wv, const float* __restrict__ wo,
                   const float* __restrict__ wi1,
                   const float* __restrict__ bk, const float* __restrict__ bv,
                   short* __restrict__ Bqkv_hi, short* __restrict__ wo_hi,
                   short* __restrict__ Wi_hi, short* __restrict__ Wi_lo,
                   float* __restrict__ bkv)
{
    const int i = blockIdx.x * 256 + threadIdx.x;
    const int which = blockIdx.y;
    if (which < 4) {
        const float* src = (which == 0) ? wq : (which == 1) ? wk : (which == 2) ? wv : wo;
        short* dst = (which == 3) ? wo_hi : (Bqkv_hi + (size_t)which * DD * DD);
        float4 v = reinterpret_cast<const float4*>(src)[i];
        short4 hh;
        hh.x = bf16rne(v.x); hh.y = bf16rne(v.y); hh.z = bf16rne(v.z); hh.w = bf16rne(v.w);
        reinterpret_cast<short4*>(dst)[i] = hh;
    } else if (which == 4) {
        if (i >= DH*DD/4) return;
        float4 v = reinterpret_cast<const float4*>(wi1)[i];
        short4 h, l;
        split1(v.x, h.x, l.x); split1(v.y, h.y, l.y);
        split1(v.z, h.z, l.z); split1(v.w, h.w, l.w);
        reinterpret_cast<short4*>(Wi_hi)[i] = h;
        reinterpret_cast<short4*>(Wi_lo)[i] = l;
    } else {
        if (i >= 2048) return;
        bkv[i] = (i < 1024) ? bk[i] : bv[i - 1024];
    }
}

// ---------------- plain bf16 MFMA GEMM, BK=64 (O-projection): C = A @ B^T + bias
__global__ __launch_bounds__(256)
void gemm_bf16(const short* __restrict__ Ahi, const short* __restrict__ Bhi,
               const float* __restrict__ bias, float* __restrict__ C,
               int M, int N, int K, int ldc)
{
    __shared__ short sAh[128*64];
    __shared__ short sBh[128*64];

    const int t = threadIdx.x;
    const int lane = t & 63, wid = t >> 6;
    const int wm = wid >> 1, wn = wid & 1;
    const int row0 = blockIdx.y * 128, col0 = blockIdx.x * 128;
    const int g = lane >> 4, r = lane & 15;
    const int lrow = lane >> 3;
    const int lslot = lane & 7;

    f32x4 acc[4][4];
    #pragma unroll
    for (int mt = 0; mt < 4; ++mt)
        #pragma unroll
        for (int nt = 0; nt < 4; ++nt) acc[mt][nt] = (f32x4){0.f, 0.f, 0.f, 0.f};

    for (int k0 = 0; k0 < K; k0 += 64) {
        #pragma unroll
        for (int e = 0; e < 4; ++e) {
            const int rl = wid * 32 + e * 8 + lrow;
            const int scol = k0 + ((lslot ^ (rl & 7)) << 3);
            const size_t ga = (size_t)(row0 + rl) * K + scol;
            const size_t gb = (size_t)(col0 + rl) * K + scol;
            const int ldso = (wid * 32 + e * 8) * 64;
            __builtin_amdgcn_global_load_lds(GLB_CAST(Ahi + ga), LDS_CAST(sAh + ldso), 16, 0, 0);
            __builtin_amdgcn_global_load_lds(GLB_CAST(Bhi + gb), LDS_CAST(sBh + ldso), 16, 0, 0);
        }
        __syncthreads();

        #pragma unroll
        for (int kk = 0; kk < 2; ++kk) {
            bf16x8 ah[4], bh[4];
            #pragma unroll
            for (int mt = 0; mt < 4; ++mt) {
                const int rw = wm * 64 + mt * 16 + r;
                ah[mt] = *reinterpret_cast<const bf16x8*>(sAh + rw * 64 + (((kk*4 + g) ^ (rw & 7)) << 3));
            }
            #pragma unroll
            for (int nt = 0; nt < 4; ++nt) {
                const int rw = wn * 64 + nt * 16 + r;
                bh[nt] = *reinterpret_cast<const bf16x8*>(sBh + rw * 64 + (((kk*4 + g) ^ (rw & 7)) << 3));
            }
            #pragma unroll
            for (int mt = 0; mt < 4; ++mt)
                #pragma unroll
                for (int nt = 0; nt < 4; ++nt)
                    acc[mt][nt] = __builtin_amdgcn_mfma_f32_16x16x32_bf16(ah[mt], bh[nt], acc[mt][nt], 0, 0, 0);
        }
        __syncthreads();
    }

    #pragma unroll
    for (int nt = 0; nt < 4; ++nt) {
        const int col = wn * 64 + nt * 16 + r;
        const float bv = bias[col0 + col];
        #pragma unroll
        for (int mt = 0; mt < 4; ++mt) {
            #pragma unroll
            for (int e = 0; e < 4; ++e) {
                const int row = row0 + wm * 64 + mt * 16 + 4 * g + e;
                C[(size_t)row * ldc + col0 + col] = acc[mt][nt][e] + bv;
            }
        }
    }
}

// ---------------- FUSED post-topk projections:
// blocks 0..511:  Q-proj tiles  Qb[8192,1024] = x_hi @ wq^T, *QK_SCALE, bf16
// blocks 512..831: gathered KV tiles -> Kg (chunk-contiguous) + Vg (transposed+swizzled) DIRECT
__global__ __launch_bounds__(256)
void qkv_fused(const short* __restrict__ x_hi, const short* __restrict__ Bqkv_hi,
               const float* __restrict__ bq, const float* __restrict__ bkv,
               const int* __restrict__ idxg,
               short* __restrict__ Qb, short* __restrict__ Kg, short* __restrict__ Vg)
{
    __shared__ __align__(16) char smem[32768];
    short* sAh = (short*)smem;
    short* sBh = sAh + 128*64;

    const int t = threadIdx.x;
    const int lane = t & 63, wid = t >> 6;
    const int wm = wid >> 1, wn = wid & 1;
    const int g = lane >> 4, r = lane & 15;
    const int lrow = lane >> 3;
    const int lslot = lane & 7;

    f32x4 acc[4][4];
    #pragma unroll
    for (int mt = 0; mt < 4; ++mt)
        #pragma unroll
        for (int nt = 0; nt < 4; ++nt) acc[mt][nt] = (f32x4){0.f, 0.f, 0.f, 0.f};

    if (blockIdx.x < 512) {
        // ---------- Q-projection tile (r16-proven body)
        const int id = blockIdx.x;
        const int row0 = (id >> 3) * 128, col0 = (id & 7) * 128;

        for (int k0 = 0; k0 < DD; k0 += 64) {
            #pragma unroll
            for (int e = 0; e < 4; ++e) {
                const int rl = wid * 32 + e * 8 + lrow;
                const int scol = k0 + ((lslot ^ (rl & 7)) << 3);
                const size_t ga = (size_t)(row0 + rl) * DD + scol;
                const size_t gb = (size_t)(col0 + rl) * DD + scol;
                const int ldso = (wid * 32 + e * 8) * 64;
                __builtin_amdgcn_global_load_lds(GLB_CAST(x_hi + ga), LDS_CAST(sAh + ldso), 16, 0, 0);
                __builtin_amdgcn_global_load_lds(GLB_CAST(Bqkv_hi + gb), LDS_CAST(sBh + ldso), 16, 0, 0);
            }
            __syncthreads();

            #pragma unroll
            for (int kk = 0; kk < 2; ++kk) {
                bf16x8 ah[4], bh[4];
                #pragma unroll
                for (int mt = 0; mt < 4; ++mt) {
                    const int rw = wm * 64 + mt * 16 + r;
                    ah[mt] = *reinterpret_cast<const bf16x8*>(sAh + rw * 64 + (((kk*4 + g) ^ (rw & 7)) << 3));
                }
                #pragma unroll
                for (int nt = 0; nt < 4; ++nt) {
                    const int rw = wn * 64 + nt * 16 + r;
                    bh[nt] = *reinterpret_cast<const bf16x8*>(sBh + rw * 64 + (((kk*4 + g) ^ (rw & 7)) << 3));
                }
                #pragma unroll
                for (int mt = 0; mt < 4; ++mt)
                    #pragma unroll
                    for (int nt = 0; nt < 4; ++nt)
                        acc[mt][nt] = __builtin_amdgcn_mfma_f32_16x16x32_bf16(ah[mt], bh[nt], acc[mt][nt], 0, 0, 0);
            }
            __syncthreads();
        }

        #pragma unroll
        for (int nt = 0; nt < 4; ++nt) {
            const int col = wn * 64 + nt * 16 + r;
            const float bv = bq[col0 + col];
            #pragma unroll
            for (int mt = 0; mt < 4; ++mt) {
                #pragma unroll
                for (int e = 0; e < 4; ++e) {
                    const int row = row0 + wm * 64 + mt * 16 + 4 * g + e;
                    Qb[(size_t)row * DD + col0 + col] = bf16rne((acc[mt][nt][e] + bv) * QK_SCALE);
                }
            }
        }
    } else {
        // ---------- gathered KV tile (r12-proven body + direct Kg/Vg epilogue)
        const int id = blockIdx.x - 512;          // 0..319
        const int row0 = (id >> 4) * 128;         // 0..2432 (20 row tiles)
        const int col0 = (id & 15) * 128;         // 0..1920 (16 col tiles)
        const short* Bw = Bqkv_hi + (size_t)DD * DD;   // [wk;wv] stacked

        size_t garow[4];
        #pragma unroll
        for (int e = 0; e < 4; ++e) {
            const int rl = row0 + wid * 32 + e * 8 + lrow;
            const int grow = (rl / KPAD) * SS + idxg[rl];
            garow[e] = (size_t)grow * DD;
        }

        for (int k0 = 0; k0 < DD; k0 += 64) {
            #pragma unroll
            for (int e = 0; e < 4; ++e) {
                const int rl = wid * 32 + e * 8 + lrow;
                const int scol = k0 + ((lslot ^ (rl & 7)) << 3);
                const size_t gb = (size_t)(col0 + rl) * DD + scol;
                const int ldso = (wid * 32 + e * 8) * 64;
                __builtin_amdgcn_global_load_lds(GLB_CAST(x_hi + garow[e] + scol), LDS_CAST(sAh + ldso), 16, 0, 0);
                __builtin_amdgcn_global_load_lds(GLB_CAST(Bw + gb), LDS_CAST(sBh + ldso), 16, 0, 0);
            }
            __syncthreads();

            #pragma unroll
            for (int kk = 0; kk < 2; ++kk) {
                bf16x8 ah[4], bh[4];
                #pragma unroll
                for (int mt = 0; mt < 4; ++mt) {
                    const int rw = wm * 64 + mt * 16 + r;
                    ah[mt] = *reinterpret_cast<const bf16x8*>(sAh + rw * 64 + (((kk*4 + g) ^ (rw & 7)) << 3));
                }
                #pragma unroll
                for (int nt = 0; nt < 4; ++nt) {
                    const int rw = wn * 64 + nt * 16 + r;
                    bh[nt] = *reinterpret_cast<const bf16x8*>(sBh + rw * 64 + (((kk*4 + g) ^ (rw & 7)) << 3));
                }
                #pragma unroll
                for (int mt = 0; mt < 4; ++mt)
                    #pragma unroll
                    for (int nt = 0; nt < 4; ++nt)
                        acc[mt][nt] = __builtin_amdgcn_mfma_f32_16x16x32_bf16(ah[mt], bh[nt], acc[mt][nt], 0, 0, 0);
            }
            __syncthreads();
        }

        // epilogue: write straight into Kg / Vg (replaces gather_kv relayout pass)
        #pragma unroll
        for (int nt = 0; nt < 4; ++nt) {
            const int col = col0 + wn * 64 + nt * 16 + r;    // 0..2047
            const float bv = bkv[col];
            const bool isK = col < 1024;
            const int cc = isK ? col : (col - 1024);
            const int h = cc >> 6, d = cc & 63;
            #pragma unroll
            for (int mt = 0; mt < 4; ++mt) {
                #pragma unroll
                for (int e = 0; e < 4; ++e) {
                    const int kvrow = row0 + wm * 64 + mt * 16 + 4 * g + e;   // 0..2559
                    const int b = kvrow / KPAD;
                    const int rem = kvrow - b * KPAD;
                    const int c = rem >> 6, key = rem & 63;
                    const size_t cbase = ((size_t)(b * HHD + h) * NCH + c) * 4096;
                    const short val = bf16rne(acc[mt][nt][e] + bv);
                    if (isK)
                        Kg[cbase + key * 64 + d] = val;
                    else
                        Vg[cbase + d * 64 + (key ^ (8 * (d >> 4)))] = val;
                }
            }
        }
    }
}

// ---------------- split-bf16 MFMA GEMM (3-term), 64x128 tile (r13-proven): indexer
template<bool RELU>
__global__ __launch_bounds__(256)
void gemm_split64(const short* __restrict__ Ahi, const short* __restrict__ Alo,
                  const short* __restrict__ Bhi, const short* __restrict__ Blo,
                  const float* __restrict__ bias, float* __restrict__ C,
                  int M, int N, int K, int ldc)
{
    __shared__ short sAh[64*32];
    __shared__ short sAl[64*32];
    __shared__ short sBh[128*32];
    __shared__ short sBl[128*32];

    const int t = threadIdx.x;
    const int lane = t & 63, wid = t >> 6;
    const int row0 = blockIdx.y * 64, col0 = blockIdx.x * 128;
    const int g = lane >> 4, r = lane & 15;
    const int srow = lane >> 2;
    const int sslot = lane & 3;

    f32x4 acc[4][2];
    #pragma unroll
    for (int mt = 0; mt < 4; ++mt)
        #pragma unroll
        for (int nt = 0; nt < 2; ++nt) acc[mt][nt] = (f32x4){0.f, 0.f, 0.f, 0.f};

    for (int k0 = 0; k0 < K; k0 += 32) {
        {
            const int rl = wid * 16 + srow;
            const int scol = k0 + ((sslot ^ ((rl >> 2) & 3)) << 3);
            const size_t ga = (size_t)(row0 + rl) * K + scol;
            const int ldso = (wid * 16) * 32;
            __builtin_amdgcn_global_load_lds(GLB_CAST(Ahi + ga), LDS_CAST(sAh + ldso), 16, 0, 0);
            __builtin_amdgcn_global_load_lds(GLB_CAST(Alo + ga), LDS_CAST(sAl + ldso), 16, 0, 0);
        }
        #pragma unroll
        for (int i = 0; i < 2; ++i) {
            const int rl = i * 64 + wid * 16 + srow;
            const int scol = k0 + ((sslot ^ ((rl >> 2) & 3)) << 3);
            const size_t gb = (size_t)(col0 + rl) * K + scol;
            const int ldso = (i * 64 + wid * 16) * 32;
            __builtin_amdgcn_global_load_lds(GLB_CAST(Bhi + gb), LDS_CAST(sBh + ldso), 16, 0, 0);
            __builtin_amdgcn_global_load_lds(GLB_CAST(Blo + gb), LDS_CAST(sBl + ldso), 16, 0, 0);
        }
        __syncthreads();

        bf16x8 ah[4], al[4], bh[2], bl[2];
        #pragma unroll
        for (int mt = 0; mt < 4; ++mt) {
            const int row = mt * 16 + r;
            const int sw = g ^ ((row >> 2) & 3);
            ah[mt] = *reinterpret_cast<const bf16x8*>(sAh + row * 32 + sw * 8);
            al[mt] = *reinterpret_cast<const bf16x8*>(sAl + row * 32 + sw * 8);
        }
        #pragma unroll
        for (int nt = 0; nt < 2; ++nt) {
            const int row = wid * 32 + nt * 16 + r;
            const int sw = g ^ ((row >> 2) & 3);
            bh[nt] = *reinterpret_cast<const bf16x8*>(sBh + row * 32 + sw * 8);
            bl[nt] = *reinterpret_cast<const bf16x8*>(sBl + row * 32 + sw * 8);
        }
        #pragma unroll
        for (int mt = 0; mt < 4; ++mt)
            #pragma unroll
            for (int nt = 0; nt < 2; ++nt) {
                acc[mt][nt] = __builtin_amdgcn_mfma_f32_16x16x32_bf16(ah[mt], bh[nt], acc[mt][nt], 0, 0, 0);
                acc[mt][nt] = __builtin_amdgcn_mfma_f32_16x16x32_bf16(ah[mt], bl[nt], acc[mt][nt], 0, 0, 0);
                acc[mt][nt] = __builtin_amdgcn_mfma_f32_16x16x32_bf16(al[mt], bh[nt], acc[mt][nt], 0, 0, 0);
            }
        __syncthreads();
    }

    #pragma unroll
    for (int nt = 0; nt < 2; ++nt) {
        const int col = wid * 32 + nt * 16 + r;
        const float bv = bias[col0 + col];
        #pragma unroll
        for (int mt = 0; mt < 4; ++mt) {
            #pragma unroll
            for (int e = 0; e < 4; ++e) {
                const int row = row0 + mt * 16 + 4 * g + e;
                float v = acc[mt][nt][e] + bv;
                if (RELU) v = fmaxf(v, 0.f);
                C[(size_t)row * ldc + col0 + col] = v;
            }
        }
    }
}

// ---------------- importance / top-k
__global__ __launch_bounds__(256)
void importance_kernel(const float* __restrict__ h, const float* __restrict__ wi2,
                       const float* __restrict__ bi2, float* __restrict__ imp)
{
    const int wid = threadIdx.x >> 6, lane = threadIdx.x & 63;
    const int row = blockIdx.x * 4 + wid;
    const float* hr = h + (size_t)row * DH;
    float s = 0.f;
    #pragma unroll
    for (int i = 0; i < DH/64; ++i)
        s = fmaf(hr[lane + i*64], wi2[lane + i*64], s);
    #pragma unroll
    for (int off = 32; off; off >>= 1) s += __shfl_down(s, off);
    if (lane == 0) imp[row] = s + bi2[0];
}

__global__ __launch_bounds__(256)
void rank_kernel(const float* __restrict__ imp, int* __restrict__ flags)
{
    __shared__ float simp[SS];
    const int b = blockIdx.y;
    const int t = threadIdx.x;
    const float* bimp = imp + b * SS;
    for (int i = t; i < SS/4; i += 256)
        reinterpret_cast<float4*>(simp)[i] = reinterpret_cast<const float4*>(bimp)[i];
    __syncthreads();

    const int i = blockIdx.x * 32 + (t >> 3);
    const int part = t & 7;
    const float v = simp[i];
    const float4* slice = reinterpret_cast<const float4*>(simp + part * (SS/8));
    const int jb = part * (SS/8);
    int rank = 0;
    #pragma unroll 8
    for (int jj = 0; jj < SS/32; ++jj) {
        const float4 u4 = slice[jj];
        const int j = jb + jj * 4;
        rank += (u4.x > v) || ((u4.x == v) && (j + 0 < i));
        rank += (u4.y > v) || ((u4.y == v) && (j + 1 < i));
        rank += (u4.z > v) || ((u4.z == v) && (j + 2 < i));
        rank += (u4.w > v) || ((u4.w == v) && (j + 3 < i));
    }
    rank += __shfl_xor(rank, 1);
    rank += __shfl_xor(rank, 2);
    rank += __shfl_xor(rank, 4);
    if (part == 0) flags[b * SS + i] = (rank < KSEL) ? 1 : 0;
}

__global__ __launch_bounds__(256)
void compact_kernel(const int* __restrict__ flags, int* __restrict__ idxg)
{
    __shared__ int sscan[SS];
    __shared__ int sidx[KSEL];
    const int b = blockIdx.x, t = threadIdx.x;
    for (int i = t; i < SS; i += 256) sscan[i] = flags[b * SS + i];
    __syncthreads();
    for (int off = 1; off < SS; off <<= 1) {
        int vals[SS/256];
        #pragma unroll
        for (int c = 0; c < SS/256; ++c) {
            const int i = t + c * 256;
            int v = sscan[i];
            if (i >= off) v += sscan[i - off];
            vals[c] = v;
        }
        __syncthreads();
        #pragma unroll
        for (int c = 0; c < SS/256; ++c) sscan[t + c * 256] = vals[c];
        __syncthreads();
    }
    for (int i = t; i < SS; i += 256) {
        const int f = flags[b * SS + i];
        if (f) sidx[sscan[i] - 1] = i;
    }
    __syncthreads();
    for (int p = t; p < KPAD; p += 256)
        idxg[b * KPAD + p] = sidx[min(p, KSEL - 1)];
}

// ---------------- MFMA sparse flash attention (round-14 proven version):
// 8 waves / 128 q-rows, exp2 softmax, truncating P->bf16, ones-column denominator
__global__ __launch_bounds__(512)
void attn_mfma(const short* __restrict__ Qb, const short* __restrict__ Kg,
               const short* __restrict__ Vg, short* __restrict__ AOhi)
{
    __shared__ short Ks[2][64*72];
    __shared__ short Vs[2][64*72];
    __shared__ short Ps[8][16*72];

    const int t = threadIdx.x;
    const int lane = t & 63, w = t >> 6;      // 8 waves
    const int g = lane >> 4, r = lane & 15;
    const int qt = blockIdx.x, h = blockIdx.y, b = blockIdx.z;
    const int q0 = qt * 128;
    short* Psw = &Ps[w][0];

    const int srow = t >> 3;           // 0..63
    const int scol = (t & 7) * 8;      // 0..56
    const short* kcbase = Kg + ((size_t)(b * HHD + h) * NCH) * 4096 + srow * 64 + scol;
    const short* vcbase = Vg + ((size_t)(b * HHD + h) * NCH) * 4096 + srow * 64 + scol;

    bf16x8 qh[2];
    {
        const short* qrow = Qb + (size_t)(b * SS + q0 + w * 16 + r) * DD + h * HD;
        qh[0] = *reinterpret_cast<const bf16x8*>(qrow + 8 * g);
        qh[1] = *reinterpret_cast<const bf16x8*>(qrow + 32 + 8 * g);
    }

    bf16x8 ones;
    #pragma unroll
    for (int j = 0; j < 8; ++j) ones[j] = (short)0x3F80;

    f32x4 oacc[4];
    #pragma unroll
    for (int dt = 0; dt < 4; ++dt) oacc[dt] = (f32x4){0.f, 0.f, 0.f, 0.f};
    f32x4 dacc = (f32x4){0.f, 0.f, 0.f, 0.f};

    bf16x8 kreg = *reinterpret_cast<const bf16x8*>(kcbase);
    bf16x8 vreg = *reinterpret_cast<const bf16x8*>(vcbase);

    for (int c = 0; c < NCH; ++c) {
        const int cur = c & 1;
        *reinterpret_cast<bf16x8*>(&Ks[cur][srow*72 + scol]) = kreg;
        *reinterpret_cast<bf16x8*>(&Vs[cur][srow*72 + scol]) = vreg;
        if (c + 1 < NCH) {
            kreg = *reinterpret_cast<const bf16x8*>(kcbase + (size_t)(c + 1) * 4096);
            vreg = *reinterpret_cast<const bf16x8*>(vcbase + (size_t)(c + 1) * 4096);
        }
        __syncthreads();

        f32x4 sa[4];
        #pragma unroll
        for (int kt = 0; kt < 4; ++kt) {
            bf16x8 kf0 = *reinterpret_cast<const bf16x8*>(&Ks[cur][(kt*16 + r)*72 + 8*g]);
            bf16x8 kf1 = *reinterpret_cast<const bf16x8*>(&Ks[cur][(kt*16 + r)*72 + 32 + 8*g]);
            f32x4 s = (f32x4){0.f, 0.f, 0.f, 0.f};
            s = __builtin_amdgcn_mfma_f32_16x16x32_bf16(qh[0], kf0, s, 0, 0, 0);
            s = __builtin_amdgcn_mfma_f32_16x16x32_bf16(qh[1], kf1, s, 0, 0, 0);
            sa[kt] = s;
        }
        if (c == NCH - 1) {
            #pragma unroll
            for (int kt = 0; kt < 4; ++kt)
                if (c*64 + kt*16 + r >= KSEL)
                    sa[kt] = (f32x4){-INFINITY, -INFINITY, -INFINITY, -INFINITY};
        }

        #pragma unroll
        for (int kt = 0; kt < 4; ++kt)
            #pragma unroll
            for (int e = 0; e < 4; ++e)
                Psw[(4*g + e)*72 + ((kt*16 + r) ^ (8*g))] =
                    (short)(__builtin_bit_cast(unsigned, exp2f(sa[kt][e])) >> 16);

        #pragma unroll
        for (int kc = 0; kc < 2; ++kc) {
            bf16x8 pf = *reinterpret_cast<const bf16x8*>(&Psw[r*72 + kc*32 + 8*(g ^ (r >> 2))]);
            dacc = __builtin_amdgcn_mfma_f32_16x16x32_bf16(pf, ones, dacc, 0, 0, 0);
            #pragma unroll
            for (int dt = 0; dt < 4; ++dt) {
                bf16x8 vf = *reinterpret_cast<const bf16x8*>(&Vs[cur][(dt*16 + r)*72 + kc*32 + 8*(g ^ dt)]);
                oacc[dt] = __builtin_amdgcn_mfma_f32_16x16x32_bf16(pf, vf, oacc[dt], 0, 0, 0);
            }
        }
    }

    #pragma unroll
    for (int dt = 0; dt < 4; ++dt)
        #pragma unroll
        for (int e = 0; e < 4; ++e) {
            const size_t a = (size_t)(b * SS + q0 + w*16 + 4*g + e) * DD + h * HD + dt*16 + r;
            AOhi[a] = bf16rne(oacc[dt][e] / dacc[e]);
        }
}

extern "C" void kernel_launch(void* const* d_in, const int* in_sizes, int n_in,
                              void* d_out, int out_size, void* d_ws, size_t ws_size,
                              hipStream_t stream)
{
    const float* x   = (const float*)d_in[0];
    const float* wq  = (const float*)d_in[1];
    const float* bq  = (const float*)d_in[2];
    const float* wk  = (const float*)d_in[3];
    const float* bk  = (const float*)d_in[4];
    const float* wv  = (const float*)d_in[5];
    const float* bv  = (const float*)d_in[6];
    const float* wo  = (const float*)d_in[7];
    const float* bo  = (const float*)d_in[8];
    const float* wi1 = (const float*)d_in[9];
    const float* bi1 = (const float*)d_in[10];
    const float* wi2 = (const float*)d_in[11];
    const float* bi2 = (const float*)d_in[12];
    float* out = (float*)d_out;

    const size_t MB = 1ull << 20;
    char* W = (char*)d_ws;
    short* x_hi  = (short*)(W + 0);          // 16 MB
    short* x_lo  = (short*)(W + 16*MB);      // 16 MB
    short* Qb    = (short*)(W + 32*MB);      // 16 MB (8192 x 1024 bf16, pre-scaled by log2e/8)
    short* Wi_hi = (short*)(W + 96*MB);      // 1 MB
    short* Wi_lo = (short*)(W + 97*MB);      // 1 MB
    short* Bqkv_hi=(short*)(W + 128*MB);     // 6 MB (wq,wk,wv hi, stacked)
    short* wo_hi = (short*)(W + 134*MB);     // 2 MB
    float* Hw    = (float*)(W + 144*MB);     // 16 MB (dead after importance_kernel)
    short* Kg    = (short*)(W + 144*MB);     // 5.25 MB (over dead Hw)
    short* Vg    = (short*)(W + 150*MB);     // 5.25 MB
    float* bkv   = (float*)(W + 160*MB);
    float* imp   = (float*)(W + 160*MB + 64*1024);
    int*   flags = (int*)(W + 160*MB + 128*1024);
    int*   idxg  = (int*)(W + 160*MB + 192*1024);
    short* AO_hi = x_hi;                     // x_hi dead after projections

    const size_t NM = (size_t)MTOT * DD;

    // 0. splits + fused bias
    split_convert<<<(NM/4 + 255)/256, 256, 0, stream>>>(x, x_hi, x_lo, NM/4);
    split_weights<<<dim3(DD*DD/4/256, 6), 256, 0, stream>>>(
        wq, wk, wv, wo, wi1, bk, bv, Bqkv_hi, wo_hi, Wi_hi, Wi_lo, bkv);

    // 1. indexer h = relu(x @ wi1^T + bi1)  -- 3-term split, 64x128 tiles
    gemm_split64<true><<<dim3(DH/128, MTOT/64), 256, 0, stream>>>(
        x_hi, x_lo, Wi_hi, Wi_lo, bi1, Hw, MTOT, DH, DD, DH);
    // 2-3. importance + top-k
    importance_kernel<<<MTOT/4, 256, 0, stream>>>(Hw, wi2, bi2, imp);
    rank_kernel<<<dim3(SS/32, BB), 256, 0, stream>>>(imp, flags);
    compact_kernel<<<BB, 256, 0, stream>>>(flags, idxg);

    // 4. fused Q projection + gathered KV projection (direct Kg/Vg layout; Hw dead)
    qkv_fused<<<832, 256, 0, stream>>>(
        x_hi, Bqkv_hi, bq, bkv, idxg, Qb, Kg, Vg);

    // 5. exp2/trunc MFMA sparse flash attention (r14), 8 waves/block -> bf16
    attn_mfma<<<dim3(SS/128, HHD, BB), 512, 0, stream>>>(Qb, Kg, Vg, AO_hi);

    // 6. output projection: 1-term bf16 BK=64
    gemm_bf16<<<dim3(DD/128, MTOT/128), 256, 0, stream>>>(
        AO_hi, wo_hi, bo, out, MTOT, DD, DD, DD);
}

// Round 18
// 198.122 us; speedup vs baseline: 1.0148x; 1.0148x over previous
//
#include <hip/hip_runtime.h>
#include <math.h>

#define BB 4
#define SS 2048
#define DD 1024
#define HHD 16      // heads
#define HD 64       // head dim
#define DH 512      // indexer hidden
#define KSEL 614    // top-k count
#define KPAD 640    // padded to multiple of 64
#define MTOT (BB*SS)
#define NCH (KPAD/64)
#define MKV (BB*KPAD)   // 2560 gathered K/V rows

typedef __attribute__((ext_vector_type(8))) short bf16x8;
typedef __attribute__((ext_vector_type(4))) float f32x4;

#define LDS_CAST(p) ((__attribute__((address_space(3))) void*)(p))
#define GLB_CAST(p) ((const __attribute__((address_space(1))) void*)(p))

// Q pre-scale: (1/8) * log2(e) so attention can use exp2 directly
#define QK_SCALE 0.18033688011112042f

// ---------------- fp32 -> bf16 helpers (RNE)
__device__ inline short bf16rne(float v)
{
    unsigned u = __builtin_bit_cast(unsigned, v);
    return (short)((u + 0x7FFFu + ((u >> 16) & 1u)) >> 16);
}

__device__ inline void split1(float v, short& h, short& l)
{
    unsigned u = __builtin_bit_cast(unsigned, v);
    unsigned hr = (u + 0x7FFFu + ((u >> 16) & 1u)) >> 16;
    h = (short)hr;
    float hf = __builtin_bit_cast(float, hr << 16);
    float res = v - hf;
    unsigned u2 = __builtin_bit_cast(unsigned, res);
    unsigned lr = (u2 + 0x7FFFu + ((u2 >> 16) & 1u)) >> 16;
    l = (short)lr;
}

__global__ __launch_bounds__(256)
void split_convert(const float* __restrict__ in, short* __restrict__ hi,
                   short* __restrict__ lo, int n4)
{
    const int i = blockIdx.x * 256 + threadIdx.x;
    if (i >= n4) return;
    float4 v = reinterpret_cast<const float4*>(in)[i];
    short4 h, l;
    split1(v.x, h.x, l.x);
    split1(v.y, h.y, l.y);
    split1(v.z, h.z, l.z);
    split1(v.w, h.w, l.w);
    reinterpret_cast<short4*>(hi)[i] = h;
    reinterpret_cast<short4*>(lo)[i] = l;
}

// fused weight splits: y=0 wq(hi), 1 wk(hi), 2 wv(hi), 3 wo(hi), 4 wi1(hi+lo), 5 bkv concat
__global__ __launch_bounds__(256)
void split_weights(const float* __restrict__ wq, const float* __restrict__ wk,
                   const float* __restrict__ wv, const float* __restrict__ wo,
                   const float* __restrict__ wi1,
                   const float* __restrict__ bk, const float* __restrict__ bv,
                   short* __restrict__ Bqkv_hi, short* __restrict__ wo_hi,
                   short* __restrict__ Wi_hi, short* __restrict__ Wi_lo,
                   float* __restrict__ bkv)
{
    const int i = blockIdx.x * 256 + threadIdx.x;
    const int which = blockIdx.y;
    if (which < 4) {
        const float* src = (which == 0) ? wq : (which == 1) ? wk : (which == 2) ? wv : wo;
        short* dst = (which == 3) ? wo_hi : (Bqkv_hi + (size_t)which * DD * DD);
        float4 v = reinterpret_cast<const float4*>(src)[i];
        short4 hh;
        hh.x = bf16rne(v.x); hh.y = bf16rne(v.y); hh.z = bf16rne(v.z); hh.w = bf16rne(v.w);
        reinterpret_cast<short4*>(dst)[i] = hh;
    } else if (which == 4) {
        if (i >= DH*DD/4) return;
        float4 v = reinterpret_cast<const float4*>(wi1)[i];
        short4 h, l;
        split1(v.x, h.x, l.x); split1(v.y, h.y, l.y);
        split1(v.z, h.z, l.z); split1(v.w, h.w, l.w);
        reinterpret_cast<short4*>(Wi_hi)[i] = h;
        reinterpret_cast<short4*>(Wi_lo)[i] = l;
    } else {
        if (i >= 2048) return;
        bkv[i] = (i < 1024) ? bk[i] : bv[i - 1024];
    }
}

// ---------------- plain bf16 MFMA GEMM, BK=64: C = A @ B^T + bias (r10-verified structure)
template<bool BF16_OUT, bool QSCALE>
__global__ __launch_bounds__(256)
void gemm_bf16(const short* __restrict__ Ahi, const short* __restrict__ Bhi,
               const float* __restrict__ bias, void* __restrict__ Cv,
               int M, int N, int K, int ldc)
{
    __shared__ short sAh[128*64];
    __shared__ short sBh[128*64];

    const int t = threadIdx.x;
    const int lane = t & 63, wid = t >> 6;
    const int wm = wid >> 1, wn = wid & 1;
    const int row0 = blockIdx.y * 128, col0 = blockIdx.x * 128;
    const int g = lane >> 4, r = lane & 15;
    const int lrow = lane >> 3;
    const int lslot = lane & 7;

    f32x4 acc[4][4];
    #pragma unroll
    for (int mt = 0; mt < 4; ++mt)
        #pragma unroll
        for (int nt = 0; nt < 4; ++nt) acc[mt][nt] = (f32x4){0.f, 0.f, 0.f, 0.f};

    for (int k0 = 0; k0 < K; k0 += 64) {
        #pragma unroll
        for (int e = 0; e < 4; ++e) {
            const int rl = wid * 32 + e * 8 + lrow;
            const int scol = k0 + ((lslot ^ (rl & 7)) << 3);
            const size_t ga = (size_t)(row0 + rl) * K + scol;
            const size_t gb = (size_t)(col0 + rl) * K + scol;
            const int ldso = (wid * 32 + e * 8) * 64;
            __builtin_amdgcn_global_load_lds(GLB_CAST(Ahi + ga), LDS_CAST(sAh + ldso), 16, 0, 0);
            __builtin_amdgcn_global_load_lds(GLB_CAST(Bhi + gb), LDS_CAST(sBh + ldso), 16, 0, 0);
        }
        __syncthreads();

        #pragma unroll
        for (int kk = 0; kk < 2; ++kk) {
            bf16x8 ah[4], bh[4];
            #pragma unroll
            for (int mt = 0; mt < 4; ++mt) {
                const int rw = wm * 64 + mt * 16 + r;
                ah[mt] = *reinterpret_cast<const bf16x8*>(sAh + rw * 64 + (((kk*4 + g) ^ (rw & 7)) << 3));
            }
            #pragma unroll
            for (int nt = 0; nt < 4; ++nt) {
                const int rw = wn * 64 + nt * 16 + r;
                bh[nt] = *reinterpret_cast<const bf16x8*>(sBh + rw * 64 + (((kk*4 + g) ^ (rw & 7)) << 3));
            }
            #pragma unroll
            for (int mt = 0; mt < 4; ++mt)
                #pragma unroll
                for (int nt = 0; nt < 4; ++nt)
                    acc[mt][nt] = __builtin_amdgcn_mfma_f32_16x16x32_bf16(ah[mt], bh[nt], acc[mt][nt], 0, 0, 0);
        }
        __syncthreads();
    }

    #pragma unroll
    for (int nt = 0; nt < 4; ++nt) {
        const int col = wn * 64 + nt * 16 + r;
        const float bv = bias[col0 + col];
        const bool qs = QSCALE && (col0 + col) < 1024;
        #pragma unroll
        for (int mt = 0; mt < 4; ++mt) {
            #pragma unroll
            for (int e = 0; e < 4; ++e) {
                const int row = row0 + wm * 64 + mt * 16 + 4 * g + e;
                float v = acc[mt][nt][e] + bv;
                if (qs) v *= QK_SCALE;
                if (BF16_OUT)
                    ((short*)Cv)[(size_t)row * ldc + col0 + col] = bf16rne(v);
                else
                    ((float*)Cv)[(size_t)row * ldc + col0 + col] = v;
            }
        }
    }
}

// ---------------- gathered KV GEMM: C[MKV,2048] = x_hi[idx rows] @ [wk;wv]^T + bias
__global__ __launch_bounds__(256)
void gemm_kv_gather(const short* __restrict__ Ahi, const short* __restrict__ Bhi,
                    const int* __restrict__ idxg, const float* __restrict__ bias,
                    short* __restrict__ C)
{
    __shared__ short sAh[128*64];
    __shared__ short sBh[128*64];

    const int K = DD, N = 2048;
    const int t = threadIdx.x;
    const int lane = t & 63, wid = t >> 6;
    const int wm = wid >> 1, wn = wid & 1;
    const int row0 = blockIdx.y * 128, col0 = blockIdx.x * 128;
    const int g = lane >> 4, r = lane & 15;
    const int lrow = lane >> 3;
    const int lslot = lane & 7;

    size_t garow[4];
    #pragma unroll
    for (int e = 0; e < 4; ++e) {
        const int rl = row0 + wid * 32 + e * 8 + lrow;
        const int grow = (rl / KPAD) * SS + idxg[rl];
        garow[e] = (size_t)grow * K;
    }

    f32x4 acc[4][4];
    #pragma unroll
    for (int mt = 0; mt < 4; ++mt)
        #pragma unroll
        for (int nt = 0; nt < 4; ++nt) acc[mt][nt] = (f32x4){0.f, 0.f, 0.f, 0.f};

    for (int k0 = 0; k0 < K; k0 += 64) {
        #pragma unroll
        for (int e = 0; e < 4; ++e) {
            const int rl = wid * 32 + e * 8 + lrow;
            const int scol = k0 + ((lslot ^ (rl & 7)) << 3);
            const size_t gb = (size_t)(col0 + rl) * K + scol;
            const int ldso = (wid * 32 + e * 8) * 64;
            __builtin_amdgcn_global_load_lds(GLB_CAST(Ahi + garow[e] + scol), LDS_CAST(sAh + ldso), 16, 0, 0);
            __builtin_amdgcn_global_load_lds(GLB_CAST(Bhi + gb), LDS_CAST(sBh + ldso), 16, 0, 0);
        }
        __syncthreads();

        #pragma unroll
        for (int kk = 0; kk < 2; ++kk) {
            bf16x8 ah[4], bh[4];
            #pragma unroll
            for (int mt = 0; mt < 4; ++mt) {
                const int rw = wm * 64 + mt * 16 + r;
                ah[mt] = *reinterpret_cast<const bf16x8*>(sAh + rw * 64 + (((kk*4 + g) ^ (rw & 7)) << 3));
            }
            #pragma unroll
            for (int nt = 0; nt < 4; ++nt) {
                const int rw = wn * 64 + nt * 16 + r;
                bh[nt] = *reinterpret_cast<const bf16x8*>(sBh + rw * 64 + (((kk*4 + g) ^ (rw & 7)) << 3));
            }
            #pragma unroll
            for (int mt = 0; mt < 4; ++mt)
                #pragma unroll
                for (int nt = 0; nt < 4; ++nt)
                    acc[mt][nt] = __builtin_amdgcn_mfma_f32_16x16x32_bf16(ah[mt], bh[nt], acc[mt][nt], 0, 0, 0);
        }
        __syncthreads();
    }

    #pragma unroll
    for (int nt = 0; nt < 4; ++nt) {
        const int col = wn * 64 + nt * 16 + r;
        const float bv = bias[col0 + col];
        #pragma unroll
        for (int mt = 0; mt < 4; ++mt) {
            #pragma unroll
            for (int e = 0; e < 4; ++e) {
                const int row = row0 + wm * 64 + mt * 16 + 4 * g + e;
                C[(size_t)row * N + col0 + col] = bf16rne(acc[mt][nt][e] + bv);
            }
        }
    }
}

// ---------------- split-bf16 MFMA GEMM (3-term), 64x128 tile (r13-proven): indexer
template<bool RELU>
__global__ __launch_bounds__(256)
void gemm_split64(const short* __restrict__ Ahi, const short* __restrict__ Alo,
                  const short* __restrict__ Bhi, const short* __restrict__ Blo,
                  const float* __restrict__ bias, float* __restrict__ C,
                  int M, int N, int K, int ldc)
{
    __shared__ short sAh[64*32];
    __shared__ short sAl[64*32];
    __shared__ short sBh[128*32];
    __shared__ short sBl[128*32];

    const int t = threadIdx.x;
    const int lane = t & 63, wid = t >> 6;
    const int row0 = blockIdx.y * 64, col0 = blockIdx.x * 128;
    const int g = lane >> 4, r = lane & 15;
    const int srow = lane >> 2;
    const int sslot = lane & 3;

    f32x4 acc[4][2];
    #pragma unroll
    for (int mt = 0; mt < 4; ++mt)
        #pragma unroll
        for (int nt = 0; nt < 2; ++nt) acc[mt][nt] = (f32x4){0.f, 0.f, 0.f, 0.f};

    for (int k0 = 0; k0 < K; k0 += 32) {
        {
            const int rl = wid * 16 + srow;
            const int scol = k0 + ((sslot ^ ((rl >> 2) & 3)) << 3);
            const size_t ga = (size_t)(row0 + rl) * K + scol;
            const int ldso = (wid * 16) * 32;
            __builtin_amdgcn_global_load_lds(GLB_CAST(Ahi + ga), LDS_CAST(sAh + ldso), 16, 0, 0);
            __builtin_amdgcn_global_load_lds(GLB_CAST(Alo + ga), LDS_CAST(sAl + ldso), 16, 0, 0);
        }
        #pragma unroll
        for (int i = 0; i < 2; ++i) {
            const int rl = i * 64 + wid * 16 + srow;
            const int scol = k0 + ((sslot ^ ((rl >> 2) & 3)) << 3);
            const size_t gb = (size_t)(col0 + rl) * K + scol;
            const int ldso = (i * 64 + wid * 16) * 32;
            __builtin_amdgcn_global_load_lds(GLB_CAST(Bhi + gb), LDS_CAST(sBh + ldso), 16, 0, 0);
            __builtin_amdgcn_global_load_lds(GLB_CAST(Blo + gb), LDS_CAST(sBl + ldso), 16, 0, 0);
        }
        __syncthreads();

        bf16x8 ah[4], al[4], bh[2], bl[2];
        #pragma unroll
        for (int mt = 0; mt < 4; ++mt) {
            const int row = mt * 16 + r;
            const int sw = g ^ ((row >> 2) & 3);
            ah[mt] = *reinterpret_cast<const bf16x8*>(sAh + row * 32 + sw * 8);
            al[mt] = *reinterpret_cast<const bf16x8*>(sAl + row * 32 + sw * 8);
        }
        #pragma unroll
        for (int nt = 0; nt < 2; ++nt) {
            const int row = wid * 32 + nt * 16 + r;
            const int sw = g ^ ((row >> 2) & 3);
            bh[nt] = *reinterpret_cast<const bf16x8*>(sBh + row * 32 + sw * 8);
            bl[nt] = *reinterpret_cast<const bf16x8*>(sBl + row * 32 + sw * 8);
        }
        #pragma unroll
        for (int mt = 0; mt < 4; ++mt)
            #pragma unroll
            for (int nt = 0; nt < 2; ++nt) {
                acc[mt][nt] = __builtin_amdgcn_mfma_f32_16x16x32_bf16(ah[mt], bh[nt], acc[mt][nt], 0, 0, 0);
                acc[mt][nt] = __builtin_amdgcn_mfma_f32_16x16x32_bf16(ah[mt], bl[nt], acc[mt][nt], 0, 0, 0);
                acc[mt][nt] = __builtin_amdgcn_mfma_f32_16x16x32_bf16(al[mt], bh[nt], acc[mt][nt], 0, 0, 0);
            }
        __syncthreads();
    }

    #pragma unroll
    for (int nt = 0; nt < 2; ++nt) {
        const int col = wid * 32 + nt * 16 + r;
        const float bv = bias[col0 + col];
        #pragma unroll
        for (int mt = 0; mt < 4; ++mt) {
            #pragma unroll
            for (int e = 0; e < 4; ++e) {
                const int row = row0 + mt * 16 + 4 * g + e;
                float v = acc[mt][nt][e] + bv;
                if (RELU) v = fmaxf(v, 0.f);
                C[(size_t)row * ldc + col0 + col] = v;
            }
        }
    }
}

// ---------------- importance / top-k
__global__ __launch_bounds__(256)
void importance_kernel(const float* __restrict__ h, const float* __restrict__ wi2,
                       const float* __restrict__ bi2, float* __restrict__ imp)
{
    const int wid = threadIdx.x >> 6, lane = threadIdx.x & 63;
    const int row = blockIdx.x * 4 + wid;
    const float* hr = h + (size_t)row * DH;
    float s = 0.f;
    #pragma unroll
    for (int i = 0; i < DH/64; ++i)
        s = fmaf(hr[lane + i*64], wi2[lane + i*64], s);
    #pragma unroll
    for (int off = 32; off; off >>= 1) s += __shfl_down(s, off);
    if (lane == 0) imp[row] = s + bi2[0];
}

__global__ __launch_bounds__(256)
void rank_kernel(const float* __restrict__ imp, int* __restrict__ flags)
{
    __shared__ float simp[SS];
    const int b = blockIdx.y;
    const int t = threadIdx.x;
    const float* bimp = imp + b * SS;
    for (int i = t; i < SS/4; i += 256)
        reinterpret_cast<float4*>(simp)[i] = reinterpret_cast<const float4*>(bimp)[i];
    __syncthreads();

    const int i = blockIdx.x * 32 + (t >> 3);
    const int part = t & 7;
    const float v = simp[i];
    const float4* slice = reinterpret_cast<const float4*>(simp + part * (SS/8));
    const int jb = part * (SS/8);
    int rank = 0;
    #pragma unroll 8
    for (int jj = 0; jj < SS/32; ++jj) {
        const float4 u4 = slice[jj];
        const int j = jb + jj * 4;
        rank += (u4.x > v) || ((u4.x == v) && (j + 0 < i));
        rank += (u4.y > v) || ((u4.y == v) && (j + 1 < i));
        rank += (u4.z > v) || ((u4.z == v) && (j + 2 < i));
        rank += (u4.w > v) || ((u4.w == v) && (j + 3 < i));
    }
    rank += __shfl_xor(rank, 1);
    rank += __shfl_xor(rank, 2);
    rank += __shfl_xor(rank, 4);
    if (part == 0) flags[b * SS + i] = (rank < KSEL) ? 1 : 0;
}

__global__ __launch_bounds__(256)
void compact_kernel(const int* __restrict__ flags, int* __restrict__ idxg)
{
    __shared__ int sscan[SS];
    __shared__ int sidx[KSEL];
    const int b = blockIdx.x, t = threadIdx.x;
    for (int i = t; i < SS; i += 256) sscan[i] = flags[b * SS + i];
    __syncthreads();
    for (int off = 1; off < SS; off <<= 1) {
        int vals[SS/256];
        #pragma unroll
        for (int c = 0; c < SS/256; ++c) {
            const int i = t + c * 256;
            int v = sscan[i];
            if (i >= off) v += sscan[i - off];
            vals[c] = v;
        }
        __syncthreads();
        #pragma unroll
        for (int c = 0; c < SS/256; ++c) sscan[t + c * 256] = vals[c];
        __syncthreads();
    }
    for (int i = t; i < SS; i += 256) {
        const int f = flags[b * SS + i];
        if (f) sidx[sscan[i] - 1] = i;
    }
    __syncthreads();
    for (int p = t; p < KPAD; p += 256)
        idxg[b * KPAD + p] = sidx[min(p, KSEL - 1)];
}

// ---------------- K/V relayout from compact KVc (r12-proven)
__global__ __launch_bounds__(256)
void gather_kv(const short* __restrict__ KVc, short* __restrict__ Kg,
               short* __restrict__ Vg)
{
    __shared__ short Vs[64*72];
    const int t = threadIdx.x;
    const int c = blockIdx.x, h = blockIdx.y, b = blockIdx.z;
    const int srow = t >> 2;
    const int sq4  = t & 3;

    const size_t cbase = ((size_t)(b * HHD + h) * NCH + c) * 4096;

    const short* kb = KVc + (size_t)(b * KPAD + c * 64 + srow) * 2048 + h * HD + sq4 * 16;
    bf16x8 k0 = *reinterpret_cast<const bf16x8*>(kb);
    bf16x8 k1 = *reinterpret_cast<const bf16x8*>(kb + 8);
    short* kout = Kg + cbase + srow * HD + sq4 * 16;
    *reinterpret_cast<bf16x8*>(kout)     = k0;
    *reinterpret_cast<bf16x8*>(kout + 8) = k1;

    const short* vbp = kb + 1024;
    bf16x8 v0 = *reinterpret_cast<const bf16x8*>(vbp);
    bf16x8 v1 = *reinterpret_cast<const bf16x8*>(vbp + 8);
    #pragma unroll
    for (int j = 0; j < 8; ++j) {
        Vs[(sq4 * 16 + j) * 72 + srow]     = v0[j];
        Vs[(sq4 * 16 + 8 + j) * 72 + srow] = v1[j];
    }
    __syncthreads();

    const int x = 8 * (srow >> 4);
    short* vout = Vg + cbase + srow * 64;
    *reinterpret_cast<bf16x8*>(vout + ((sq4 * 16)     ^ x)) = *reinterpret_cast<const bf16x8*>(&Vs[srow * 72 + sq4 * 16]);
    *reinterpret_cast<bf16x8*>(vout + ((sq4 * 16 + 8) ^ x)) = *reinterpret_cast<const bf16x8*>(&Vs[srow * 72 + sq4 * 16 + 8]);
}

// ---------------- MFMA sparse flash attention: 8 waves x TWO 128-row q-tiles per block
// (256 q-rows share each staged K/V chunk -> staging/barriers per q-row halved).
// exp2 softmax, truncating P->bf16, ones-column denominator, double-buffered LDS.
__global__ __launch_bounds__(512)
void attn_mfma(const short* __restrict__ Qb, const short* __restrict__ Kg,
               const short* __restrict__ Vg, short* __restrict__ AOhi)
{
    __shared__ short Ks[2][64*72];
    __shared__ short Vs[2][64*72];
    __shared__ short Ps[8][16*72];

    const int t = threadIdx.x;
    const int lane = t & 63, w = t >> 6;      // 8 waves
    const int g = lane >> 4, r = lane & 15;
    const int qt = blockIdx.x, h = blockIdx.y, b = blockIdx.z;
    const int q0 = qt * 256;
    short* Psw = &Ps[w][0];

    const int srow = t >> 3;           // 0..63
    const int scol = (t & 7) * 8;      // 0..56
    const short* kcbase = Kg + ((size_t)(b * HHD + h) * NCH) * 4096 + srow * 64 + scol;
    const short* vcbase = Vg + ((size_t)(b * HHD + h) * NCH) * 4096 + srow * 64 + scol;

    bf16x8 qh[2][2];
    #pragma unroll
    for (int tq = 0; tq < 2; ++tq) {
        const short* qrow = Qb + (size_t)(b * SS + q0 + tq * 128 + w * 16 + r) * DD + h * HD;
        qh[tq][0] = *reinterpret_cast<const bf16x8*>(qrow + 8 * g);
        qh[tq][1] = *reinterpret_cast<const bf16x8*>(qrow + 32 + 8 * g);
    }

    bf16x8 ones;
    #pragma unroll
    for (int j = 0; j < 8; ++j) ones[j] = (short)0x3F80;

    f32x4 oacc[2][4];
    f32x4 dacc[2];
    #pragma unroll
    for (int tq = 0; tq < 2; ++tq) {
        #pragma unroll
        for (int dt = 0; dt < 4; ++dt) oacc[tq][dt] = (f32x4){0.f, 0.f, 0.f, 0.f};
        dacc[tq] = (f32x4){0.f, 0.f, 0.f, 0.f};
    }

    bf16x8 kreg = *reinterpret_cast<const bf16x8*>(kcbase);
    bf16x8 vreg = *reinterpret_cast<const bf16x8*>(vcbase);

    for (int c = 0; c < NCH; ++c) {
        const int cur = c & 1;
        *reinterpret_cast<bf16x8*>(&Ks[cur][srow*72 + scol]) = kreg;
        *reinterpret_cast<bf16x8*>(&Vs[cur][srow*72 + scol]) = vreg;
        if (c + 1 < NCH) {
            kreg = *reinterpret_cast<const bf16x8*>(kcbase + (size_t)(c + 1) * 4096);
            vreg = *reinterpret_cast<const bf16x8*>(vcbase + (size_t)(c + 1) * 4096);
        }
        __syncthreads();

        #pragma unroll
        for (int tq = 0; tq < 2; ++tq) {
            // ---- QK^T from LDS (scores pre-scaled by log2e/8 via Q)
            f32x4 sa[4];
            #pragma unroll
            for (int kt = 0; kt < 4; ++kt) {
                bf16x8 kf0 = *reinterpret_cast<const bf16x8*>(&Ks[cur][(kt*16 + r)*72 + 8*g]);
                bf16x8 kf1 = *reinterpret_cast<const bf16x8*>(&Ks[cur][(kt*16 + r)*72 + 32 + 8*g]);
                f32x4 s = (f32x4){0.f, 0.f, 0.f, 0.f};
                s = __builtin_amdgcn_mfma_f32_16x16x32_bf16(qh[tq][0], kf0, s, 0, 0, 0);
                s = __builtin_amdgcn_mfma_f32_16x16x32_bf16(qh[tq][1], kf1, s, 0, 0, 0);
                sa[kt] = s;
            }
            if (c == NCH - 1) {
                #pragma unroll
                for (int kt = 0; kt < 4; ++kt)
                    if (c*64 + kt*16 + r >= KSEL)
                        sa[kt] = (f32x4){-INFINITY, -INFINITY, -INFINITY, -INFINITY};
            }

            // ---- p = exp2(s); truncate to bf16 (bias cancels in num/denom ratio)
            #pragma unroll
            for (int kt = 0; kt < 4; ++kt)
                #pragma unroll
                for (int e = 0; e < 4; ++e)
                    Psw[(4*g + e)*72 + ((kt*16 + r) ^ (8*g))] =
                        (short)(__builtin_bit_cast(unsigned, exp2f(sa[kt][e])) >> 16);

            // ---- PV + denominator (ones-column MFMA); in-order DS within wave
            #pragma unroll
            for (int kc = 0; kc < 2; ++kc) {
                bf16x8 pf = *reinterpret_cast<const bf16x8*>(&Psw[r*72 + kc*32 + 8*(g ^ (r >> 2))]);
                dacc[tq] = __builtin_amdgcn_mfma_f32_16x16x32_bf16(pf, ones, dacc[tq], 0, 0, 0);
                #pragma unroll
                for (int dt = 0; dt < 4; ++dt) {
                    bf16x8 vf = *reinterpret_cast<const bf16x8*>(&Vs[cur][(dt*16 + r)*72 + kc*32 + 8*(g ^ dt)]);
                    oacc[tq][dt] = __builtin_amdgcn_mfma_f32_16x16x32_bf16(pf, vf, oacc[tq][dt], 0, 0, 0);
                }
            }
        }
    }

    #pragma unroll
    for (int tq = 0; tq < 2; ++tq)
        #pragma unroll
        for (int dt = 0; dt < 4; ++dt)
            #pragma unroll
            for (int e = 0; e < 4; ++e) {
                const size_t a = (size_t)(b * SS + q0 + tq*128 + w*16 + 4*g + e) * DD + h * HD + dt*16 + r;
                AOhi[a] = bf16rne(oacc[tq][dt][e] / dacc[tq][e]);
            }
}

extern "C" void kernel_launch(void* const* d_in, const int* in_sizes, int n_in,
                              void* d_out, int out_size, void* d_ws, size_t ws_size,
                              hipStream_t stream)
{
    const float* x   = (const float*)d_in[0];
    const float* wq  = (const float*)d_in[1];
    const float* bq  = (const float*)d_in[2];
    const float* wk  = (const float*)d_in[3];
    const float* bk  = (const float*)d_in[4];
    const float* wv  = (const float*)d_in[5];
    const float* bv  = (const float*)d_in[6];
    const float* wo  = (const float*)d_in[7];
    const float* bo  = (const float*)d_in[8];
    const float* wi1 = (const float*)d_in[9];
    const float* bi1 = (const float*)d_in[10];
    const float* wi2 = (const float*)d_in[11];
    const float* bi2 = (const float*)d_in[12];
    float* out = (float*)d_out;

    const size_t MB = 1ull << 20;
    char* W = (char*)d_ws;
    short* x_hi  = (short*)(W + 0);          // 16 MB
    short* x_lo  = (short*)(W + 16*MB);      // 16 MB
    short* Qb    = (short*)(W + 32*MB);      // 16 MB (8192 x 1024 bf16, pre-scaled by log2e/8)
    short* KVc   = (short*)(W + 48*MB);      // 10.5 MB (2560 x 2048 bf16)
    short* Wi_hi = (short*)(W + 96*MB);      // 1 MB
    short* Wi_lo = (short*)(W + 97*MB);      // 1 MB
    short* Bqkv_hi=(short*)(W + 128*MB);     // 6 MB (wq,wk,wv hi, stacked)
    short* wo_hi = (short*)(W + 134*MB);     // 2 MB
    float* Hw    = (float*)(W + 144*MB);     // 16 MB (dead after importance_kernel)
    short* Kg    = (short*)(W + 144*MB);     // 5.25 MB (over dead Hw)
    short* Vg    = (short*)(W + 150*MB);     // 5.25 MB
    float* bkv   = (float*)(W + 160*MB);
    float* imp   = (float*)(W + 160*MB + 64*1024);
    int*   flags = (int*)(W + 160*MB + 128*1024);
    int*   idxg  = (int*)(W + 160*MB + 192*1024);
    short* AO_hi = x_hi;                     // x_hi dead after projections

    const size_t NM = (size_t)MTOT * DD;

    // 0. splits + fused bias
    split_convert<<<(NM/4 + 255)/256, 256, 0, stream>>>(x, x_hi, x_lo, NM/4);
    split_weights<<<dim3(DD*DD/4/256, 6), 256, 0, stream>>>(
        wq, wk, wv, wo, wi1, bk, bv, Bqkv_hi, wo_hi, Wi_hi, Wi_lo, bkv);

    // 1. indexer h = relu(x @ wi1^T + bi1)  -- 3-term split, 64x128 tiles
    gemm_split64<true><<<dim3(DH/128, MTOT/64), 256, 0, stream>>>(
        x_hi, x_lo, Wi_hi, Wi_lo, bi1, Hw, MTOT, DH, DD, DH);
    // 2-3. importance + top-k
    importance_kernel<<<MTOT/4, 256, 0, stream>>>(Hw, wi2, bi2, imp);
    rank_kernel<<<dim3(SS/32, BB), 256, 0, stream>>>(imp, flags);
    compact_kernel<<<BB, 256, 0, stream>>>(flags, idxg);

    // 4a. Q projection: 1-term bf16, pre-scaled by log2e/8 (exp2 softmax)
    gemm_bf16<true, true><<<dim3(DD/128, MTOT/128), 256, 0, stream>>>(
        x_hi, Bqkv_hi, bq, Qb, MTOT, DD, DD, DD);
    // 4b. gathered K/V projection: only the 2560 selected rows
    gemm_kv_gather<<<dim3(2048/128, MKV/128), 256, 0, stream>>>(
        x_hi, Bqkv_hi + (size_t)DD*DD, idxg, bkv, KVc);

    // 4c. relayout K/V chunk-contiguous
    gather_kv<<<dim3(NCH, HHD, BB), 256, 0, stream>>>(KVc, Kg, Vg);

    // 5. exp2/trunc MFMA sparse flash attention, 256 q-rows/block -> bf16
    attn_mfma<<<dim3(SS/256, HHD, BB), 512, 0, stream>>>(Qb, Kg, Vg, AO_hi);

    // 6. output projection: 1-term bf16 BK=64
    gemm_bf16<false, false><<<dim3(DD/128, MTOT/128), 256, 0, stream>>>(
        AO_hi, wo_hi, bo, out, MTOT, DD, DD, DD);
}